// Round 5
// baseline (523.646 us; speedup 1.0000x reference)
//
#include <hip/hip_runtime.h>
#include <hip/hip_bf16.h>
#include <math.h>

#define HIDN  2048
#define NH    16
#define NKV   4
#define LORA  512
#define D_ROPE 64
#define D_NOPE 128
#define D_VV  128
#define D_QKD 192
#define BATCH 2
#define SEQ   2048
#define NTOK  (BATCH*SEQ)          // 4096
#define QKV_W (NH*D_QKD + LORA)    // 3584
#define KW    (NKV*D_QKD)          // 768
#define VW    (NKV*D_VV)           // 512
#define AW    (NH*D_VV)            // 2048
#define QSCALE 0.07216878364870323f   // 1/sqrt(192)
#define LOG2E  1.4426950408889634f

typedef __attribute__((ext_vector_type(8))) __bf16 bf16x8;
typedef __attribute__((ext_vector_type(4))) float f32x4;

static __device__ __forceinline__ unsigned short f2bf(float f) {
    unsigned int u = __builtin_bit_cast(unsigned int, f);
    u += 0x7fffu + ((u >> 16) & 1u);          // round-to-nearest-even
    return (unsigned short)(u >> 16);
}
static __device__ __forceinline__ float bf2f(unsigned short v) {
    unsigned int u = (unsigned int)v << 16;
    return __builtin_bit_cast(float, u);
}
static __device__ __forceinline__ void gl2lds16(const unsigned short* g, unsigned short* l) {
    __builtin_amdgcn_global_load_lds(
        (const __attribute__((address_space(1))) unsigned int*)g,
        (__attribute__((address_space(3))) unsigned int*)l, 16, 0, 0);
}

// ---------------------------------------------------------------------------
// Transpose + cast: W fp32 [K][N] -> Wt bf16 [N][K]; optional column scale.
// ---------------------------------------------------------------------------
__global__ __launch_bounds__(256) void transpose_w(
    const float* __restrict__ W, unsigned short* __restrict__ Wt,
    int K, int N, int scale_ncols, float scale)
{
    __shared__ float T[64][68];
    const int tid = threadIdx.x;
    const int k0 = blockIdx.y * 64, n0 = blockIdx.x * 64;
    const int rr = tid >> 4;
    const int c4 = (tid & 15) * 4;

#pragma unroll
    for (int i = 0; i < 4; ++i) {
        int r = rr + 16 * i;
        *(float4*)&T[r][c4] = *(const float4*)&W[(size_t)(k0 + r) * N + n0 + c4];
    }
    __syncthreads();
#pragma unroll
    for (int i = 0; i < 4; ++i) {
        int nr = rr + 16 * i;
        float sc = (n0 + nr < scale_ncols) ? scale : 1.0f;
        unsigned short tmp[4];
#pragma unroll
        for (int j = 0; j < 4; ++j) tmp[j] = f2bf(T[c4 + j][nr] * sc);
        unsigned int p0 = (unsigned int)tmp[0] | ((unsigned int)tmp[1] << 16);
        unsigned int p1 = (unsigned int)tmp[2] | ((unsigned int)tmp[3] << 16);
        *(uint2*)&Wt[(size_t)(n0 + nr) * K + k0 + c4] = make_uint2(p0, p1);
    }
}

__global__ __launch_bounds__(256) void cast_plain(const float* __restrict__ src,
                                                  unsigned short* __restrict__ dst)
{
    int idx = blockIdx.x * 256 + threadIdx.x;
    float4 v = *(const float4*)&src[(size_t)idx * 4];
    unsigned int p0 = (unsigned int)f2bf(v.x) | ((unsigned int)f2bf(v.y) << 16);
    unsigned int p1 = (unsigned int)f2bf(v.z) | ((unsigned int)f2bf(v.w) << 16);
    *(uint2*)&dst[(size_t)idx * 4] = make_uint2(p0, p1);
}

// ---------------------------------------------------------------------------
// bf16 MFMA GEMM (m97 structure): C = A[M,K] @ Bt[N,K]^T.
// OUT_MODE: 0 = fp32 C[M][N], 1 = bf16 C[M][N], 2 = bf16 transposed Ct[N][M].
// ---------------------------------------------------------------------------
template<int OUT_MODE>
__global__ __launch_bounds__(256) void gemm_bt(
    const unsigned short* __restrict__ A,
    const unsigned short* __restrict__ Bt,
    void* __restrict__ C,
    int K, int lda, int ldb, int ldc)
{
    __shared__ __align__(16) unsigned short As[128 * 32];
    __shared__ __align__(16) unsigned short Bs[128 * 32];

    const int tid  = threadIdx.x;
    const int w    = tid >> 6;
    const int lane = tid & 63;
    const int quad = lane >> 4;
    const int l15  = lane & 15;
    const int brow = blockIdx.y * 128;
    const int bcol = blockIdx.x * 128;
    const int wr   = (w >> 1) * 64;
    const int wc   = (w & 1) * 64;

    const int srow = lane >> 2;
    const int sseg = (lane & 3) * 8;
    const int r0   = w * 32;

    f32x4 acc[4][4];
#pragma unroll
    for (int mt = 0; mt < 4; ++mt)
#pragma unroll
        for (int nt = 0; nt < 4; ++nt) acc[mt][nt] = (f32x4){0.f, 0.f, 0.f, 0.f};

    const unsigned short* Ab = A  + (size_t)(brow + r0 + srow) * lda + sseg;
    const unsigned short* Bb = Bt + (size_t)(bcol + r0 + srow) * ldb + sseg;

    for (int k0 = 0; k0 < K; k0 += 32) {
        __syncthreads();
        gl2lds16(Ab + k0,                     As + r0 * 32);
        gl2lds16(Ab + k0 + (size_t)16 * lda,  As + (r0 + 16) * 32);
        gl2lds16(Bb + k0,                     Bs + r0 * 32);
        gl2lds16(Bb + k0 + (size_t)16 * ldb,  Bs + (r0 + 16) * 32);
        __syncthreads();

        bf16x8 af[4], bfr[4];
#pragma unroll
        for (int mt = 0; mt < 4; ++mt)
            af[mt] = __builtin_bit_cast(bf16x8,
                *(const uint4*)(As + (wr + mt * 16 + l15) * 32 + quad * 8));
#pragma unroll
        for (int nt = 0; nt < 4; ++nt)
            bfr[nt] = __builtin_bit_cast(bf16x8,
                *(const uint4*)(Bs + (wc + nt * 16 + l15) * 32 + quad * 8));
#pragma unroll
        for (int mt = 0; mt < 4; ++mt)
#pragma unroll
            for (int nt = 0; nt < 4; ++nt)
                acc[mt][nt] = __builtin_amdgcn_mfma_f32_16x16x32_bf16(
                    af[mt], bfr[nt], acc[mt][nt], 0, 0, 0);
    }

    if (OUT_MODE == 2) {
#pragma unroll
        for (int mt = 0; mt < 4; ++mt) {
            int row0 = brow + wr + mt * 16 + quad * 4;
#pragma unroll
            for (int nt = 0; nt < 4; ++nt) {
                int col = bcol + wc + nt * 16 + l15;
                unsigned int p0 = (unsigned int)f2bf(acc[mt][nt][0]) |
                                  ((unsigned int)f2bf(acc[mt][nt][1]) << 16);
                unsigned int p1 = (unsigned int)f2bf(acc[mt][nt][2]) |
                                  ((unsigned int)f2bf(acc[mt][nt][3]) << 16);
                *(uint2*)&((unsigned short*)C)[(size_t)col * ldc + row0] = make_uint2(p0, p1);
            }
        }
    } else {
#pragma unroll
        for (int mt = 0; mt < 4; ++mt)
#pragma unroll
            for (int i = 0; i < 4; ++i) {
                size_t row = (size_t)(brow + wr + mt * 16 + quad * 4 + i);
#pragma unroll
                for (int nt = 0; nt < 4; ++nt) {
                    int col = bcol + wc + nt * 16 + l15;
                    if (OUT_MODE == 1)
                        ((unsigned short*)C)[row * ldc + col] = f2bf(acc[mt][nt][i]);
                    else
                        ((float*)C)[row * ldc + col] = acc[mt][nt][i];
                }
            }
    }
}

// ---------------------------------------------------------------------------
// RoPE in-place on bf16 q (inside qkvb) and bf16 k (kb).
// ---------------------------------------------------------------------------
__global__ __launch_bounds__(256) void rope_bf16(unsigned short* __restrict__ qkvb,
                                                 unsigned short* __restrict__ kb)
{
    int idx = blockIdx.x * 256 + threadIdx.x;
    int i    = idx & 31;
    int head = (idx >> 5) % 20;
    int t    = idx / (20 * 32);
    if (t >= NTOK) return;
    int pos = t & (SEQ - 1);

    const float LOG_BASE_OVER_32 = 0.28782313662425572f; // ln(10000)/32
    float ang = (float)pos * __expf(-(float)i * LOG_BASE_OVER_32);
    float c = cosf(ang);
    float sn = sinf(ang);

    unsigned short* p;
    if (head < NH) p = qkvb + (size_t)t * QKV_W + head * D_QKD + D_NOPE;
    else           p = kb   + (size_t)t * KW    + (head - NH) * D_QKD + D_NOPE;

    float x1 = bf2f(p[i]), x2 = bf2f(p[i + 32]);
    p[i]      = f2bf(x1 * c - x2 * sn);
    p[i + 32] = f2bf(x2 * c + x1 * sn);
}

// ---------------------------------------------------------------------------
// MFMA flash attention, causal, GQA. Fixed m=0 softmax in exp2 domain
// (log2(e) folded into q scale). Per-tile: double-buffered staging through
// VGPRs (t+1 loads issued before computing t), zero cross-lane ops in the
// K-loop (l-reduction deferred to the epilogue).
// ---------------------------------------------------------------------------
__global__ __launch_bounds__(256) void attn_mfma(
    const unsigned short* __restrict__ qkvb,
    const unsigned short* __restrict__ kb,
    const unsigned short* __restrict__ vt,
    unsigned short* __restrict__ attnb)
{
    __shared__ __align__(16) unsigned short Ks[32 * 200];   // [kpos][192+8]
    __shared__ __align__(16) unsigned short Vt[128 * 40];   // [d][32+8]
    __shared__ __align__(16) unsigned short Ps[4 * 16 * 40];

    const int tid  = threadIdx.x;
    const int w    = tid >> 6;
    const int lane = tid & 63;
    const int quad = lane >> 4;
    const int l15  = lane & 15;
    const int h    = blockIdx.y;
    const int b    = blockIdx.z;
    const int kvh  = h >> 2;

    // Tile-invariant staging coordinates
    int krow[3], kdc[3], vd[2], vseg[2];
#pragma unroll
    for (int it = 0; it < 3; ++it) {
        int c = tid + it * 256;
        krow[it] = c / 24; kdc[it] = (c % 24) * 8;
    }
#pragma unroll
    for (int it = 0; it < 2; ++it) {
        int c = tid + it * 256;
        vd[it] = c >> 2; vseg[it] = (c & 3) * 8;
    }
    const unsigned short* kp0 = kb + (size_t)(b * SEQ) * KW + kvh * D_QKD;
    const unsigned short* vp0 = vt + (size_t)(kvh * 128) * NTOK + b * SEQ;

    for (int ph = 0; ph < 2; ++ph) {
        const int qt   = ph ? (31 - (int)blockIdx.x) : (int)blockIdx.x;
        const int q0   = qt * 64;
        const int q0w  = q0 + w * 16;
        const int wmax = q0w + 15;

        bf16x8 qf[6];
        {
            const unsigned short* qp =
                qkvb + (size_t)(b * SEQ + q0w + l15) * QKV_W + h * D_QKD + quad * 8;
#pragma unroll
            for (int t = 0; t < 6; ++t)
                qf[t] = __builtin_bit_cast(bf16x8, *(const uint4*)(qp + t * 32));
        }

        f32x4 o[8];
#pragma unroll
        for (int c = 0; c < 8; ++c) o[c] = (f32x4){0.f, 0.f, 0.f, 0.f};
        float lp[4] = {0.f, 0.f, 0.f, 0.f};

        const int nt = 2 * qt + 2;

        // Preload + stage tile 0
        uint4 kreg[3], vreg[2];
#pragma unroll
        for (int it = 0; it < 3; ++it)
            kreg[it] = *(const uint4*)(kp0 + (size_t)krow[it] * KW + kdc[it]);
#pragma unroll
        for (int it = 0; it < 2; ++it)
            vreg[it] = *(const uint4*)(vp0 + (size_t)vd[it] * NTOK + vseg[it]);
#pragma unroll
        for (int it = 0; it < 3; ++it)
            *(uint4*)(Ks + krow[it] * 200 + kdc[it]) = kreg[it];
#pragma unroll
        for (int it = 0; it < 2; ++it)
            *(uint4*)(Vt + vd[it] * 40 + vseg[it]) = vreg[it];
        __syncthreads();

        for (int tk = 0; tk < nt; ++tk) {
            const int k0 = tk * 32;

            // Issue next tile's global loads (consumed after the compute barrier)
            if (tk + 1 < nt) {
                const int k1 = k0 + 32;
#pragma unroll
                for (int it = 0; it < 3; ++it)
                    kreg[it] = *(const uint4*)(kp0 + (size_t)(k1 + krow[it]) * KW + kdc[it]);
#pragma unroll
                for (int it = 0; it < 2; ++it)
                    vreg[it] = *(const uint4*)(vp0 + (size_t)vd[it] * NTOK + k1 + vseg[it]);
            }

            if (k0 <= wmax) {
                // ---- scores: S[16q][32k] = Q @ K^T (log2 domain) ----
                f32x4 s[2];
#pragma unroll
                for (int j = 0; j < 2; ++j) {
                    f32x4 acc = {0.f, 0.f, 0.f, 0.f};
                    const unsigned short* kr = Ks + (j * 16 + l15) * 200 + quad * 8;
#pragma unroll
                    for (int t = 0; t < 6; ++t) {
                        bf16x8 kf = __builtin_bit_cast(bf16x8, *(const uint4*)(kr + t * 32));
                        acc = __builtin_amdgcn_mfma_f32_16x16x32_bf16(qf[t], kf, acc, 0, 0, 0);
                    }
                    s[j] = acc;
                }

                // ---- softmax, fixed m=0, exp2; per-lane partial l only ----
#pragma unroll
                for (int i = 0; i < 4; ++i) {
                    int row = q0w + quad * 4 + i;
                    float p0 = (k0 + l15      <= row) ? __builtin_amdgcn_exp2f(s[0][i]) : 0.f;
                    float p1 = (k0 + 16 + l15 <= row) ? __builtin_amdgcn_exp2f(s[1][i]) : 0.f;
                    s[0][i] = p0; s[1][i] = p1;
                    lp[i] += p0 + p1;
                }

                // ---- P: C-layout -> LDS -> A-layout frag ----
                unsigned short* pw = Ps + w * (16 * 40);
#pragma unroll
                for (int i = 0; i < 4; ++i) {
                    int row = quad * 4 + i;
                    pw[row * 40 + l15]      = f2bf(s[0][i]);
                    pw[row * 40 + 16 + l15] = f2bf(s[1][i]);
                }
                __asm__ volatile("s_waitcnt lgkmcnt(0)" ::: "memory");
                bf16x8 pa = __builtin_bit_cast(bf16x8, *(const uint4*)(pw + l15 * 40 + quad * 8));

                // ---- PV: 8 MFMAs ----
#pragma unroll
                for (int c = 0; c < 8; ++c) {
                    bf16x8 vf = __builtin_bit_cast(bf16x8,
                        *(const uint4*)(Vt + (c * 16 + l15) * 40 + quad * 8));
                    o[c] = __builtin_amdgcn_mfma_f32_16x16x32_bf16(pa, vf, o[c], 0, 0, 0);
                }
            }

            __syncthreads();            // all waves done reading Ks/Vt for tile tk
            if (tk + 1 < nt) {
#pragma unroll
                for (int it = 0; it < 3; ++it)
                    *(uint4*)(Ks + krow[it] * 200 + kdc[it]) = kreg[it];
#pragma unroll
                for (int it = 0; it < 2; ++it)
                    *(uint4*)(Vt + vd[it] * 40 + vseg[it]) = vreg[it];
            }
            __syncthreads();            // staged tile tk+1 visible
        }

        // ---- epilogue: reduce l across the 16-lane groups, write out ----
#pragma unroll
        for (int i = 0; i < 4; ++i) {
            float sum = lp[i];
            sum += __shfl_xor(sum, 1);
            sum += __shfl_xor(sum, 2);
            sum += __shfl_xor(sum, 4);
            sum += __shfl_xor(sum, 8);
            float inv = 1.0f / sum;
            size_t rowoff = (size_t)(b * SEQ + q0w + quad * 4 + i) * AW + h * D_VV + l15;
#pragma unroll
            for (int c = 0; c < 8; ++c)
                attnb[rowoff + c * 16] = f2bf(o[c][i] * inv);
        }
        __syncthreads();   // protect Ks/Vt before next phase preloads
    }
}

// ---------------------------------------------------------------------------
extern "C" void kernel_launch(void* const* d_in, const int* in_sizes, int n_in,
                              void* d_out, int out_size, void* d_ws, size_t ws_size,
                              hipStream_t stream)
{
    const float* X     = (const float*)d_in[0];
    const float* Wqkv  = (const float*)d_in[1];
    const float* Wk_up = (const float*)d_in[2];
    const float* Wv_up = (const float*)d_in[3];
    const float* Wo    = (const float*)d_in[4];
    float* out = (float*)d_out;

    unsigned short* Xb    = (unsigned short*)d_ws;                   // [4096][2048]
    unsigned short* Wqt   = Xb    + (size_t)NTOK * HIDN;             // [3584][2048]
    unsigned short* Wkt   = Wqt   + (size_t)QKV_W * HIDN;            // [768][512]
    unsigned short* Wvt   = Wkt   + (size_t)KW * LORA;               // [512][512]
    unsigned short* Wot   = Wvt   + (size_t)VW * LORA;               // [2048][2048]
    unsigned short* qkvb  = Wot   + (size_t)HIDN * AW;               // [4096][3584]
    unsigned short* kb    = qkvb  + (size_t)NTOK * QKV_W;            // [4096][768]
    unsigned short* vtb   = kb    + (size_t)NTOK * KW;               // [512][4096] (V^T)
    unsigned short* attnb = vtb   + (size_t)VW * NTOK;               // [4096][2048]

    cast_plain<<<NTOK * HIDN / 4 / 256, 256, 0, stream>>>(X, Xb);
    // q columns pre-scaled by (1/sqrt(192)) * log2(e): softmax runs in exp2 domain
    transpose_w<<<dim3(QKV_W / 64, HIDN / 64), 256, 0, stream>>>(
        Wqkv, Wqt, HIDN, QKV_W, NH * D_QKD, QSCALE * LOG2E);
    transpose_w<<<dim3(KW / 64, LORA / 64), 256, 0, stream>>>(Wk_up, Wkt, LORA, KW, 0, 1.0f);
    transpose_w<<<dim3(VW / 64, LORA / 64), 256, 0, stream>>>(Wv_up, Wvt, LORA, VW, 0, 1.0f);
    transpose_w<<<dim3(AW / 64, HIDN / 64), 256, 0, stream>>>(Wo, Wot, HIDN, AW, 0, 1.0f);

    // qkvb = Xb @ Wqt^T (bf16; q cols pre-scaled)
    gemm_bt<1><<<dim3(QKV_W / 128, NTOK / 128), 256, 0, stream>>>(
        Xb, Wqt, qkvb, HIDN, HIDN, HIDN, QKV_W);

    // kb = c_kv @ Wkt^T (bf16) ; vt = (c_kv @ Wvt^T)^T (bf16, transposed out)
    gemm_bt<1><<<dim3(KW / 128, NTOK / 128), 256, 0, stream>>>(
        qkvb + NH * D_QKD, Wkt, kb, LORA, QKV_W, LORA, KW);
    gemm_bt<2><<<dim3(VW / 128, NTOK / 128), 256, 0, stream>>>(
        qkvb + NH * D_QKD, Wvt, vtb, LORA, QKV_W, LORA, NTOK);

    rope_bf16<<<(NTOK * 20 * 32 + 255) / 256, 256, 0, stream>>>(qkvb, kb);

    attn_mfma<<<dim3(16, NH, BATCH), 256, 0, stream>>>(qkvb, kb, vtb, attnb);

    gemm_bt<0><<<dim3(HIDN / 128, NTOK / 128), 256, 0, stream>>>(
        attnb, Wot, out, AW, AW, AW, HIDN);
}

// Round 6
// 422.322 us; speedup vs baseline: 1.2399x; 1.2399x over previous
//
#include <hip/hip_runtime.h>
#include <hip/hip_bf16.h>
#include <math.h>

#define HIDN  2048
#define NH    16
#define NKV   4
#define LORA  512
#define D_ROPE 64
#define D_NOPE 128
#define D_VV  128
#define D_QKD 192
#define BATCH 2
#define SEQ   2048
#define NTOK  (BATCH*SEQ)          // 4096
#define QKV_W (NH*D_QKD + LORA)    // 3584
#define KW    (NKV*D_QKD)          // 768
#define VW    (NKV*D_VV)           // 512
#define AW    (NH*D_VV)            // 2048
#define QSCALE 0.07216878364870323f   // 1/sqrt(192)
#define LOG2E  1.4426950408889634f

typedef __attribute__((ext_vector_type(8))) __bf16 bf16x8;
typedef __attribute__((ext_vector_type(4))) float f32x4;

static __device__ __forceinline__ unsigned short f2bf(float f) {
    unsigned int u = __builtin_bit_cast(unsigned int, f);
    u += 0x7fffu + ((u >> 16) & 1u);          // round-to-nearest-even
    return (unsigned short)(u >> 16);
}
static __device__ __forceinline__ float bf2f(unsigned short v) {
    unsigned int u = (unsigned int)v << 16;
    return __builtin_bit_cast(float, u);
}
static __device__ __forceinline__ void gl2lds16(const unsigned short* g, unsigned short* l) {
    __builtin_amdgcn_global_load_lds(
        (const __attribute__((address_space(1))) unsigned int*)g,
        (__attribute__((address_space(3))) unsigned int*)l, 16, 0, 0);
}

// ---------------------------------------------------------------------------
// Transpose + cast: W fp32 [K][N] -> Wt bf16 [N][K]; optional column scale.
// ---------------------------------------------------------------------------
__global__ __launch_bounds__(256) void transpose_w(
    const float* __restrict__ W, unsigned short* __restrict__ Wt,
    int K, int N, int scale_ncols, float scale)
{
    __shared__ float T[64][68];
    const int tid = threadIdx.x;
    const int k0 = blockIdx.y * 64, n0 = blockIdx.x * 64;
    const int rr = tid >> 4;
    const int c4 = (tid & 15) * 4;

#pragma unroll
    for (int i = 0; i < 4; ++i) {
        int r = rr + 16 * i;
        *(float4*)&T[r][c4] = *(const float4*)&W[(size_t)(k0 + r) * N + n0 + c4];
    }
    __syncthreads();
#pragma unroll
    for (int i = 0; i < 4; ++i) {
        int nr = rr + 16 * i;
        float sc = (n0 + nr < scale_ncols) ? scale : 1.0f;
        unsigned short tmp[4];
#pragma unroll
        for (int j = 0; j < 4; ++j) tmp[j] = f2bf(T[c4 + j][nr] * sc);
        unsigned int p0 = (unsigned int)tmp[0] | ((unsigned int)tmp[1] << 16);
        unsigned int p1 = (unsigned int)tmp[2] | ((unsigned int)tmp[3] << 16);
        *(uint2*)&Wt[(size_t)(n0 + nr) * K + k0 + c4] = make_uint2(p0, p1);
    }
}

__global__ __launch_bounds__(256) void cast_plain(const float* __restrict__ src,
                                                  unsigned short* __restrict__ dst)
{
    int idx = blockIdx.x * 256 + threadIdx.x;
    float4 v = *(const float4*)&src[(size_t)idx * 4];
    unsigned int p0 = (unsigned int)f2bf(v.x) | ((unsigned int)f2bf(v.y) << 16);
    unsigned int p1 = (unsigned int)f2bf(v.z) | ((unsigned int)f2bf(v.w) << 16);
    *(uint2*)&dst[(size_t)idx * 4] = make_uint2(p0, p1);
}

// ---------------------------------------------------------------------------
// bf16 MFMA GEMM (m97 structure): C = A[M,K] @ Bt[N,K]^T.
// OUT_MODE: 0 = fp32 C[M][N], 1 = bf16 C[M][N], 2 = bf16 transposed Ct[N][M].
// ---------------------------------------------------------------------------
template<int OUT_MODE>
__global__ __launch_bounds__(256) void gemm_bt(
    const unsigned short* __restrict__ A,
    const unsigned short* __restrict__ Bt,
    void* __restrict__ C,
    int K, int lda, int ldb, int ldc)
{
    __shared__ __align__(16) unsigned short As[128 * 32];
    __shared__ __align__(16) unsigned short Bs[128 * 32];

    const int tid  = threadIdx.x;
    const int w    = tid >> 6;
    const int lane = tid & 63;
    const int quad = lane >> 4;
    const int l15  = lane & 15;
    const int brow = blockIdx.y * 128;
    const int bcol = blockIdx.x * 128;
    const int wr   = (w >> 1) * 64;
    const int wc   = (w & 1) * 64;

    const int srow = lane >> 2;
    const int sseg = (lane & 3) * 8;
    const int r0   = w * 32;

    f32x4 acc[4][4];
#pragma unroll
    for (int mt = 0; mt < 4; ++mt)
#pragma unroll
        for (int nt = 0; nt < 4; ++nt) acc[mt][nt] = (f32x4){0.f, 0.f, 0.f, 0.f};

    const unsigned short* Ab = A  + (size_t)(brow + r0 + srow) * lda + sseg;
    const unsigned short* Bb = Bt + (size_t)(bcol + r0 + srow) * ldb + sseg;

    for (int k0 = 0; k0 < K; k0 += 32) {
        __syncthreads();
        gl2lds16(Ab + k0,                     As + r0 * 32);
        gl2lds16(Ab + k0 + (size_t)16 * lda,  As + (r0 + 16) * 32);
        gl2lds16(Bb + k0,                     Bs + r0 * 32);
        gl2lds16(Bb + k0 + (size_t)16 * ldb,  Bs + (r0 + 16) * 32);
        __syncthreads();

        bf16x8 af[4], bfr[4];
#pragma unroll
        for (int mt = 0; mt < 4; ++mt)
            af[mt] = __builtin_bit_cast(bf16x8,
                *(const uint4*)(As + (wr + mt * 16 + l15) * 32 + quad * 8));
#pragma unroll
        for (int nt = 0; nt < 4; ++nt)
            bfr[nt] = __builtin_bit_cast(bf16x8,
                *(const uint4*)(Bs + (wc + nt * 16 + l15) * 32 + quad * 8));
#pragma unroll
        for (int mt = 0; mt < 4; ++mt)
#pragma unroll
            for (int nt = 0; nt < 4; ++nt)
                acc[mt][nt] = __builtin_amdgcn_mfma_f32_16x16x32_bf16(
                    af[mt], bfr[nt], acc[mt][nt], 0, 0, 0);
    }

    if (OUT_MODE == 2) {
#pragma unroll
        for (int mt = 0; mt < 4; ++mt) {
            int row0 = brow + wr + mt * 16 + quad * 4;
#pragma unroll
            for (int nt = 0; nt < 4; ++nt) {
                int col = bcol + wc + nt * 16 + l15;
                unsigned int p0 = (unsigned int)f2bf(acc[mt][nt][0]) |
                                  ((unsigned int)f2bf(acc[mt][nt][1]) << 16);
                unsigned int p1 = (unsigned int)f2bf(acc[mt][nt][2]) |
                                  ((unsigned int)f2bf(acc[mt][nt][3]) << 16);
                *(uint2*)&((unsigned short*)C)[(size_t)col * ldc + row0] = make_uint2(p0, p1);
            }
        }
    } else {
#pragma unroll
        for (int mt = 0; mt < 4; ++mt)
#pragma unroll
            for (int i = 0; i < 4; ++i) {
                size_t row = (size_t)(brow + wr + mt * 16 + quad * 4 + i);
#pragma unroll
                for (int nt = 0; nt < 4; ++nt) {
                    int col = bcol + wc + nt * 16 + l15;
                    if (OUT_MODE == 1)
                        ((unsigned short*)C)[row * ldc + col] = f2bf(acc[mt][nt][i]);
                    else
                        ((float*)C)[row * ldc + col] = acc[mt][nt][i];
                }
            }
    }
}

// ---------------------------------------------------------------------------
// RoPE in-place on bf16 q (inside qkvb) and bf16 k (kb).
// ---------------------------------------------------------------------------
__global__ __launch_bounds__(256) void rope_bf16(unsigned short* __restrict__ qkvb,
                                                 unsigned short* __restrict__ kb)
{
    int idx = blockIdx.x * 256 + threadIdx.x;
    int i    = idx & 31;
    int head = (idx >> 5) % 20;
    int t    = idx / (20 * 32);
    if (t >= NTOK) return;
    int pos = t & (SEQ - 1);

    const float LOG_BASE_OVER_32 = 0.28782313662425572f; // ln(10000)/32
    float ang = (float)pos * __expf(-(float)i * LOG_BASE_OVER_32);
    float c = cosf(ang);
    float sn = sinf(ang);

    unsigned short* p;
    if (head < NH) p = qkvb + (size_t)t * QKV_W + head * D_QKD + D_NOPE;
    else           p = kb   + (size_t)t * KW    + (head - NH) * D_QKD + D_NOPE;

    float x1 = bf2f(p[i]), x2 = bf2f(p[i + 32]);
    p[i]      = f2bf(x1 * c - x2 * sn);
    p[i + 32] = f2bf(x2 * c + x1 * sn);
}

// ---------------------------------------------------------------------------
// MFMA flash attention, causal, GQA. Fixed m=0 softmax in exp2 domain.
// Double-buffered K/V staging via global_load_lds DMA (no staging VGPRs).
// XOR-swizzled unpadded LDS layouts (DMA needs contiguity; swizzle keeps
// ds_read_b128 fragment reads at free 2-way bank aliasing):
//   K: [row][24 blk16], stored blk = gblk ^ (row&7)
//   V: [d][4 blk16],    stored blk = gblk ^ ((d>>1)&3)
// One __syncthreads per K-tile (its vmcnt drain completes the DMA).
// ---------------------------------------------------------------------------
__global__ __launch_bounds__(256) void attn_mfma(
    const unsigned short* __restrict__ qkvb,
    const unsigned short* __restrict__ kb,
    const unsigned short* __restrict__ vt,
    unsigned short* __restrict__ attnb)
{
    __shared__ __align__(16) unsigned short KsL[2 * 32 * 192];  // 2 x 12 KB
    __shared__ __align__(16) unsigned short VtL[2 * 128 * 32];  // 2 x 8 KB
    __shared__ __align__(16) unsigned short Ps[4 * 16 * 40];    // 5 KB

    const int tid  = threadIdx.x;
    const int w    = tid >> 6;
    const int lane = tid & 63;
    const int quad = lane >> 4;
    const int l15  = lane & 15;
    const int h    = blockIdx.y;
    const int b    = blockIdx.z;
    const int kvh  = h >> 2;
    const int x7   = l15 & 7;             // K read swizzle
    const int vx   = (l15 >> 1) & 3;      // V read swizzle

    // Per-lane DMA source offsets (shorts), tile-invariant.
    int koff[3], voff[2];
#pragma unroll
    for (int it = 0; it < 3; ++it) {
        int bidx = (w * 3 + it) * 64 + lane;      // 16B-block index in K tile
        int row  = bidx / 24;
        int sblk = bidx - row * 24;
        int gblk = sblk ^ (row & 7);
        koff[it] = row * KW + gblk * 8;
    }
#pragma unroll
    for (int it = 0; it < 2; ++it) {
        int bidx = (w * 2 + it) * 64 + lane;      // 16B-block index in V tile
        int row  = bidx >> 2;
        int gblk = (bidx & 3) ^ ((row >> 1) & 3);
        voff[it] = row * NTOK + gblk * 8;
    }
    const unsigned short* kp0 = kb + (size_t)(b * SEQ) * KW + kvh * D_QKD;
    const unsigned short* vp0 = vt + (size_t)(kvh * 128) * NTOK + b * SEQ;

    for (int ph = 0; ph < 2; ++ph) {
        const int qt   = ph ? (31 - (int)blockIdx.x) : (int)blockIdx.x;
        const int q0   = qt * 64;
        const int q0w  = q0 + w * 16;
        const int wmax = q0w + 15;

        bf16x8 qf[6];
        {
            const unsigned short* qp =
                qkvb + (size_t)(b * SEQ + q0w + l15) * QKV_W + h * D_QKD + quad * 8;
#pragma unroll
            for (int t = 0; t < 6; ++t)
                qf[t] = __builtin_bit_cast(bf16x8, *(const uint4*)(qp + t * 32));
        }

        f32x4 o[8];
#pragma unroll
        for (int c = 0; c < 8; ++c) o[c] = (f32x4){0.f, 0.f, 0.f, 0.f};
        float lp[4] = {0.f, 0.f, 0.f, 0.f};

        const int nt = 2 * qt + 2;

        // DMA tile 0 into buffer 0
        {
            const unsigned short* ks = kp0;
            const unsigned short* vs = vp0;
#pragma unroll
            for (int it = 0; it < 3; ++it)
                gl2lds16(ks + koff[it], KsL + (w * 3 + it) * 512);
#pragma unroll
            for (int it = 0; it < 2; ++it)
                gl2lds16(vs + voff[it], VtL + (w * 2 + it) * 512);
        }
        __syncthreads();   // vmcnt drain: tile 0 staged

        for (int tk = 0; tk < nt; ++tk) {
            const int k0  = tk * 32;
            const int cur = tk & 1;

            // Issue DMA for tile tk+1 into the other buffer (no wait, no regs)
            if (tk + 1 < nt) {
                const int nxt = cur ^ 1;
                const unsigned short* ks = kp0 + (size_t)(k0 + 32) * KW;
                const unsigned short* vs = vp0 + (k0 + 32);
#pragma unroll
                for (int it = 0; it < 3; ++it)
                    gl2lds16(ks + koff[it], KsL + nxt * (32 * 192) + (w * 3 + it) * 512);
#pragma unroll
                for (int it = 0; it < 2; ++it)
                    gl2lds16(vs + voff[it], VtL + nxt * (128 * 32) + (w * 2 + it) * 512);
            }

            if (k0 <= wmax) {
                const unsigned short* Kc = KsL + cur * (32 * 192);
                const unsigned short* Vc = VtL + cur * (128 * 32);

                // ---- scores: S[16q][32k] = Q @ K^T (log2 domain) ----
                f32x4 s[2];
#pragma unroll
                for (int j = 0; j < 2; ++j) {
                    f32x4 acc = {0.f, 0.f, 0.f, 0.f};
                    const unsigned short* kr = Kc + (j * 16 + l15) * 192;
#pragma unroll
                    for (int t = 0; t < 6; ++t) {
                        int sblk = (quad + 4 * t) ^ x7;
                        bf16x8 kf = __builtin_bit_cast(bf16x8, *(const uint4*)(kr + sblk * 8));
                        acc = __builtin_amdgcn_mfma_f32_16x16x32_bf16(qf[t], kf, acc, 0, 0, 0);
                    }
                    s[j] = acc;
                }

                // ---- softmax, fixed m=0, exp2; per-lane partial l only ----
#pragma unroll
                for (int i = 0; i < 4; ++i) {
                    int row = q0w + quad * 4 + i;
                    float p0 = (k0 + l15      <= row) ? __builtin_amdgcn_exp2f(s[0][i]) : 0.f;
                    float p1 = (k0 + 16 + l15 <= row) ? __builtin_amdgcn_exp2f(s[1][i]) : 0.f;
                    s[0][i] = p0; s[1][i] = p1;
                    lp[i] += p0 + p1;
                }

                // ---- P: C-layout -> LDS -> A-layout frag ----
                unsigned short* pw = Ps + w * (16 * 40);
#pragma unroll
                for (int i = 0; i < 4; ++i) {
                    int row = quad * 4 + i;
                    pw[row * 40 + l15]      = f2bf(s[0][i]);
                    pw[row * 40 + 16 + l15] = f2bf(s[1][i]);
                }
                __asm__ volatile("s_waitcnt lgkmcnt(0)" ::: "memory");
                bf16x8 pa = __builtin_bit_cast(bf16x8, *(const uint4*)(pw + l15 * 40 + quad * 8));

                // ---- PV: 8 MFMAs, swizzled V frags ----
#pragma unroll
                for (int c = 0; c < 8; ++c) {
                    bf16x8 vf = __builtin_bit_cast(bf16x8,
                        *(const uint4*)(Vc + (c * 16 + l15) * 32 + ((quad ^ vx) * 8)));
                    o[c] = __builtin_amdgcn_mfma_f32_16x16x32_bf16(pa, vf, o[c], 0, 0, 0);
                }
            }

            __syncthreads();   // waves done with buf cur; DMA for tk+1 drained
        }

        // ---- epilogue: reduce l across the 16-lane groups, write out ----
#pragma unroll
        for (int i = 0; i < 4; ++i) {
            float sum = lp[i];
            sum += __shfl_xor(sum, 1);
            sum += __shfl_xor(sum, 2);
            sum += __shfl_xor(sum, 4);
            sum += __shfl_xor(sum, 8);
            float inv = 1.0f / sum;
            size_t rowoff = (size_t)(b * SEQ + q0w + quad * 4 + i) * AW + h * D_VV + l15;
#pragma unroll
            for (int c = 0; c < 8; ++c)
                attnb[rowoff + c * 16] = f2bf(o[c][i] * inv);
        }
        __syncthreads();   // protect LDS before next phase restages
    }
}

// ---------------------------------------------------------------------------
extern "C" void kernel_launch(void* const* d_in, const int* in_sizes, int n_in,
                              void* d_out, int out_size, void* d_ws, size_t ws_size,
                              hipStream_t stream)
{
    const float* X     = (const float*)d_in[0];
    const float* Wqkv  = (const float*)d_in[1];
    const float* Wk_up = (const float*)d_in[2];
    const float* Wv_up = (const float*)d_in[3];
    const float* Wo    = (const float*)d_in[4];
    float* out = (float*)d_out;

    unsigned short* Xb    = (unsigned short*)d_ws;                   // [4096][2048]
    unsigned short* Wqt   = Xb    + (size_t)NTOK * HIDN;             // [3584][2048]
    unsigned short* Wkt   = Wqt   + (size_t)QKV_W * HIDN;            // [768][512]
    unsigned short* Wvt   = Wkt   + (size_t)KW * LORA;               // [512][512]
    unsigned short* Wot   = Wvt   + (size_t)VW * LORA;               // [2048][2048]
    unsigned short* qkvb  = Wot   + (size_t)HIDN * AW;               // [4096][3584]
    unsigned short* kb    = qkvb  + (size_t)NTOK * QKV_W;            // [4096][768]
    unsigned short* vtb   = kb    + (size_t)NTOK * KW;               // [512][4096] (V^T)
    unsigned short* attnb = vtb   + (size_t)VW * NTOK;               // [4096][2048]

    cast_plain<<<NTOK * HIDN / 4 / 256, 256, 0, stream>>>(X, Xb);
    // q columns pre-scaled by (1/sqrt(192)) * log2(e): softmax runs in exp2 domain
    transpose_w<<<dim3(QKV_W / 64, HIDN / 64), 256, 0, stream>>>(
        Wqkv, Wqt, HIDN, QKV_W, NH * D_QKD, QSCALE * LOG2E);
    transpose_w<<<dim3(KW / 64, LORA / 64), 256, 0, stream>>>(Wk_up, Wkt, LORA, KW, 0, 1.0f);
    transpose_w<<<dim3(VW / 64, LORA / 64), 256, 0, stream>>>(Wv_up, Wvt, LORA, VW, 0, 1.0f);
    transpose_w<<<dim3(AW / 64, HIDN / 64), 256, 0, stream>>>(Wo, Wot, HIDN, AW, 0, 1.0f);

    // qkvb = Xb @ Wqt^T (bf16; q cols pre-scaled)
    gemm_bt<1><<<dim3(QKV_W / 128, NTOK / 128), 256, 0, stream>>>(
        Xb, Wqt, qkvb, HIDN, HIDN, HIDN, QKV_W);

    // kb = c_kv @ Wkt^T (bf16) ; vt = (c_kv @ Wvt^T)^T (bf16, transposed out)
    gemm_bt<1><<<dim3(KW / 128, NTOK / 128), 256, 0, stream>>>(
        qkvb + NH * D_QKD, Wkt, kb, LORA, QKV_W, LORA, KW);
    gemm_bt<2><<<dim3(VW / 128, NTOK / 128), 256, 0, stream>>>(
        qkvb + NH * D_QKD, Wvt, vtb, LORA, QKV_W, LORA, NTOK);

    rope_bf16<<<(NTOK * 20 * 32 + 255) / 256, 256, 0, stream>>>(qkvb, kb);

    attn_mfma<<<dim3(16, NH, BATCH), 256, 0, stream>>>(qkvb, kb, vtb, attnb);

    gemm_bt<0><<<dim3(HIDN / 128, NTOK / 128), 256, 0, stream>>>(
        attnb, Wot, out, AW, AW, AW, HIDN);
}